// Round 1
// baseline (121.902 us; speedup 1.0000x reference)
//
#include <hip/hip_runtime.h>
#include <math.h>

// ---------------------------------------------------------------------------
// NormalDistributionChecker1D, round 13 — single fused kernel.
// r12 (118us) = harness fill (~41-62us, untouchable) + pass_hist + reduce_hist
// (16MB histp round-trip) + finalize + 3 launches.
// This round: integer addition is associative -> per-block hist merge can be
// GLOBAL atomicAdd into H[8192] directly (deterministic, no fp ordering
// issue). Kills histp (16MB traffic) and the reduce_hist kernel. finalize is
// folded in via last-block-done ticket (agent-scope atomics + threadfence for
// cross-XCD visibility per Guideline 16). Tiny init kernel zeroes H+ticket
// (harness poisons ws, cannot assume zeros).
//   init   (8 blk x 1024): H[8192]=0, ticket=0.
//   fused  (256 blk x 1024): sum/sumsq + 8192-bin LDS histogram of x
//     (w=1/512 over [-8,8), LDS int atomics -> deterministic); flush via
//     global atomicAdd into H (staggered start per block to decontend hot
//     center lines); stats partials -> part1 (agent-scope atomic stores);
//     ticket; last block: stats from part1 (fixed-order fp64), then
//     cum[k] = sum_b H[b] * avg2(sigma_k at slope-shifted GL2 nodes of bin b)
//     (cancels 1st+2nd order discretization error), chi2 + softmax epilogue.
// All cross-block data: integer counts or fixed-order fp64 -> deterministic.
// ---------------------------------------------------------------------------

#if __has_builtin(__builtin_amdgcn_exp2f)
#define EXP2F(x) __builtin_amdgcn_exp2f(x)
#else
#define EXP2F(x) exp2f(x)
#endif
#if __has_builtin(__builtin_amdgcn_rcpf)
#define RCPF(x) __builtin_amdgcn_rcpf(x)
#else
#define RCPF(x) (1.0f / (x))
#endif

#define NBLK 256     // fused-kernel blocks (1/CU), 1024 threads each
#define ABLOCK 1024
#define NBINS 8192   // w = 1/512 over [-8, 8)

static __device__ __forceinline__ double wave_reduce_d(double v) {
#pragma unroll
    for (int off = 32; off > 0; off >>= 1) v += __shfl_down(v, off);
    return v;
}

__device__ __constant__ double d_ZS[9] = {
    -1.2815516, -0.8416212, -0.5244005, -0.2533471, 0.0,
    0.2533471,  0.5244005,  0.8416212,  1.2815516};

__device__ void epilogue(const double* cum, float* out, int n) {
    const double CRIT[9] = {14.683657, 12.242145, 10.656372, 9.413640, 8.342832,
                            7.357034,  6.393306,  5.380053,  4.168159};
    const double nd = (double)n;
    double actual[10];
    actual[0] = cum[0];
#pragma unroll
    for (int k = 1; k < 9; ++k) actual[k] = cum[k] - cum[k - 1];
    actual[9] = nd - cum[8];
    const double expected = nd * (double)0.1f;
    const double denom = expected + 1e-7;
    double chi2 = 0.0;
#pragma unroll
    for (int j = 0; j < 10; ++j) {
        double d = actual[j] - expected;
        chi2 += d * d / denom;
    }
    double dneg[9], m = -1e300;
#pragma unroll
    for (int k = 0; k < 9; ++k) {
        dneg[k] = -fabs(chi2 - CRIT[k]);
        if (dneg[k] > m) m = dneg[k];
    }
    double W = 0.0, PQ = 0.0;
#pragma unroll
    for (int k = 0; k < 9; ++k) {
        double w = exp(dneg[k] - m);
        W += w;
        PQ += w * (0.1 * (double)(k + 1));
    }
    double p = 1.0 - PQ / W;
    double excess = (chi2 - 14.683657) / 100.0;
    if (excess < 0.0) excess = 0.0;
    out[0] = (float)(p + excess);
}

// ws layout: part1 = 512 doubles | H = NBINS u32 (32KB) | ticket u32
__global__ __launch_bounds__(ABLOCK) void init_kernel(unsigned int* __restrict__ H,
                                                      unsigned int* __restrict__ ticket) {
    const int t = blockIdx.x * ABLOCK + threadIdx.x;
    if (t < NBINS) H[t] = 0u;
    if (t == 0) *ticket = 0u;
}

__global__ __launch_bounds__(ABLOCK) void fused_kernel(
    const float* __restrict__ x, double* __restrict__ part1,
    unsigned int* __restrict__ H, unsigned int* __restrict__ ticket,
    float* __restrict__ out, int n) {
    __shared__ unsigned int hist[NBINS];  // 32 KB
    __shared__ double smd[16][9];
    __shared__ double sMV[2];  // mu, 1/sigma
    __shared__ int sLast;
    const int tx = threadIdx.x;
    const int lane = tx & 63, wid = tx >> 6;

#pragma unroll
    for (int j = 0; j < NBINS / ABLOCK; ++j) hist[tx + j * ABLOCK] = 0u;
    __syncthreads();

    float fs = 0.f, fss = 0.f;
    auto process = [&](float v) {
        fs += v;
        fss = fmaf(v, v, fss);
        // bin = floor((v + 8) * 512), clamped
        int b = (int)fmaf(v, 512.0f, 4096.0f);
        b = b < 0 ? 0 : (b > NBINS - 1 ? NBINS - 1 : b);
        atomicAdd(&hist[b], 1u);  // LDS integer atomic: deterministic
    };

    const int tid = blockIdx.x * ABLOCK + tx;
    const int nthreads = NBLK * ABLOCK;
    const int n4 = n >> 2;
    const float4* __restrict__ x4 = (const float4*)x;
    for (int i = tid; i < n4; i += nthreads) {  // 16 iters at n=16.7M
        float4 v = x4[i];
        process(v.x); process(v.y); process(v.z); process(v.w);
    }
    if (blockIdx.x == 0 && tx == 0) {  // n%4 scalar tail (empty at n=16.7M)
        for (int j = n4 << 2; j < n; ++j) process(x[j]);
    }
    __syncthreads();

    // ---- flush: merge per-block hist into global H via integer atomics ----
    // (associative -> deterministic). Stagger start region per block so 256
    // blocks don't all hammer the same cache lines in lockstep.
#pragma unroll
    for (int j = 0; j < NBINS / ABLOCK; ++j) {
        const int jj = (j + (int)blockIdx.x) & (NBINS / ABLOCK - 1);
        const int b = tx + jj * ABLOCK;
        const unsigned int h = hist[b];
        if (h) atomicAdd(&H[b], h);  // device-scope by default
    }

    // ---- stats partials ----
    double s = wave_reduce_d((double)fs);
    double ss = wave_reduce_d((double)fss);
    if (lane == 0) { smd[wid][0] = s; smd[wid][1] = ss; }
    __syncthreads();
    if (tx == 0) {
        double ts = 0.0, tss = 0.0;
#pragma unroll
        for (int w = 0; w < 16; ++w) { ts += smd[w][0]; tss += smd[w][1]; }
        // agent-scope atomic stores: visible across XCD L2s after the fence
        __hip_atomic_store(&part1[2 * blockIdx.x], ts, __ATOMIC_RELAXED,
                           __HIP_MEMORY_SCOPE_AGENT);
        __hip_atomic_store(&part1[2 * blockIdx.x + 1], tss, __ATOMIC_RELAXED,
                           __HIP_MEMORY_SCOPE_AGENT);
    }

    // ---- arrive: last-block-done ticket ----
    __syncthreads();  // barrier drains each thread's outstanding vmem ops
    if (tx == 0) {
        __threadfence();  // release (agent scope)
        const unsigned int prev = __hip_atomic_fetch_add(
            ticket, 1u, __ATOMIC_ACQ_REL, __HIP_MEMORY_SCOPE_AGENT);
        sLast = (prev == (unsigned int)(NBLK - 1));
    }
    __syncthreads();
    if (!sLast) return;
    __threadfence();  // acquire: invalidate stale cache state before re-reads

    // =================== finalize (last block only) ===================
    // stats: fixed-assignment fp64 reduce of part1 (deterministic)
    double ps = 0.0, pss = 0.0;
    if (tx < NBLK) {
        ps = __hip_atomic_load(&part1[2 * tx], __ATOMIC_RELAXED,
                               __HIP_MEMORY_SCOPE_AGENT);
        pss = __hip_atomic_load(&part1[2 * tx + 1], __ATOMIC_RELAXED,
                                __HIP_MEMORY_SCOPE_AGENT);
    }
    double rs = wave_reduce_d(ps);
    double rss = wave_reduce_d(pss);
    __syncthreads();  // smd reuse
    if (lane == 0) { smd[wid][0] = rs; smd[wid][1] = rss; }
    __syncthreads();
    if (tx == 0) {
        double ts = 0.0, tss = 0.0;
#pragma unroll
        for (int w = 0; w < 16; ++w) { ts += smd[w][0]; tss += smd[w][1]; }
        const double nd = (double)n;
        const double mean = ts / nd;
        const double var = (tss - ts * ts / nd) / (nd - 1.0);  // ddof=1
        sMV[0] = mean;
        sMV[1] = 1.0 / sqrt(var);
    }
    __syncthreads();
    const double mu = sMV[0], isig = sMV[1];
    const double Ld = 144.26950408889634;        // 100 * log2(e)
    const double wz = (1.0 / 512.0) * isig;      // bin width in z units
    const double wz2_12 = wz * wz / 12.0;        // density-slope shift scale
    const double hgl = wz * 0.28867513459481287; // GL2 half-offset w/(2*sqrt(3))

    double acc[9];
#pragma unroll
    for (int k = 0; k < 9; ++k) acc[k] = 0.0;

    for (int b = tx; b < NBINS; b += ABLOCK) {  // 8 bins per thread
        const unsigned int h = __hip_atomic_load(&H[b], __ATOMIC_RELAXED,
                                                 __HIP_MEMORY_SCOPE_AGENT);
        if (h == 0u) continue;
        const double dh = (double)h;
        const double c = (double)b * (1.0 / 512.0) + (0.5 / 512.0 - 8.0);
        const double zc = (c - mu) * isig;
        const double zctr = zc - zc * wz2_12;  // + slope shift (-z * wz^2/12)
        const double z1 = zctr - hgl, z2 = zctr + hgl;
#pragma unroll
        for (int k = 0; k < 9; ++k) {
            // sigma(100*(zs-z)) = 1/(1 + 2^(Ld*(z-zs))); z math fp64, eval fp32
            const float t1 = EXP2F((float)(Ld * (z1 - d_ZS[k])));
            const float t2 = EXP2F((float)(Ld * (z2 - d_ZS[k])));
            const double sg =
                0.5 * ((double)RCPF(1.0f + t1) + (double)RCPF(1.0f + t2));
            acc[k] += dh * sg;
        }
    }

    __syncthreads();  // smd reuse
#pragma unroll
    for (int k = 0; k < 9; ++k) {
        double r = wave_reduce_d(acc[k]);
        if (lane == 0) smd[wid][k] = r;
    }
    __syncthreads();
    if (tx == 0) {
        double cum[9];
#pragma unroll
        for (int k = 0; k < 9; ++k) {
            double t = 0.0;
#pragma unroll
            for (int w = 0; w < 16; ++w) t += smd[w][k];
            cum[k] = t;
        }
        epilogue(cum, out, n);
    }
}

extern "C" void kernel_launch(void* const* d_in, const int* in_sizes, int n_in,
                              void* d_out, int out_size, void* d_ws, size_t ws_size,
                              hipStream_t stream) {
    const float* x = (const float*)d_in[0];
    const int n = in_sizes[0];
    double* part1 = (double*)d_ws;                    // 512 doubles
    unsigned int* H = (unsigned int*)(part1 + 512);   // NBINS u32 (32KB)
    unsigned int* ticket = H + NBINS;                 // 1 u32

    init_kernel<<<8, ABLOCK, 0, stream>>>(H, ticket);
    fused_kernel<<<NBLK, ABLOCK, 0, stream>>>(x, part1, H, ticket,
                                              (float*)d_out, n);
}